// Round 1
// baseline (298.468 us; speedup 1.0000x reference)
//
#include <hip/hip_runtime.h>
#include <hip/hip_bf16.h>
#include <cmath>

#define V_   10000
#define D_   300
#define P_   100
#define B_   32
#define T_   2048
#define C_   600   // P * (MAXL-1)
#define NC_  2

// ---------------------------------------------------------------------------
// K1: mt[v][c] = max( (diags @ emb)[c][v] + bias[c], wc_flat[c] )
// Block tile: 128 v  x 64 c, 256 threads, micro-tile 8v x 4c per thread.
// emb is (D,V) row-major (coalesced over v); diags is (C,D) row-major.
// ---------------------------------------------------------------------------
__global__ __launch_bounds__(256) void k_gemm(const float* __restrict__ emb,
                                              const float* __restrict__ diags,
                                              const float* __restrict__ bias,
                                              const float* __restrict__ wc,
                                              float* __restrict__ mt) {
    __shared__ __align__(16) float embT[30][128];
    __shared__ __align__(16) float diagT[30][64];
    const int v0  = blockIdx.x * 128;
    const int c0  = blockIdx.y * 64;
    const int tid = threadIdx.x;

    float acc[8][4];
    #pragma unroll
    for (int i = 0; i < 8; i++)
        #pragma unroll
        for (int j = 0; j < 4; j++) acc[i][j] = 0.f;

    const int vv8 = (tid & 15) * 8;
    const int cc4 = (tid >> 4) * 4;

    for (int d0 = 0; d0 < D_; d0 += 30) {
        // stage emb tile [30][128] (lanes read consecutive v -> coalesced)
        for (int q = tid; q < 30 * 128; q += 256) {
            int dd = q >> 7, vv = q & 127;
            int v = v0 + vv;
            embT[dd][vv] = (v < V_) ? emb[(d0 + dd) * V_ + v] : 0.f;
        }
        // stage diags tile transposed -> diagT[dd][cc]
        for (int q = tid; q < 30 * 64; q += 256) {
            int cc = q / 30, dd = q - cc * 30;
            int c = c0 + cc;
            diagT[dd][cc] = (c < C_) ? diags[c * D_ + d0 + dd] : 0.f;
        }
        __syncthreads();

        #pragma unroll
        for (int dd = 0; dd < 30; dd++) {
            float4 e0 = *(const float4*)&embT[dd][vv8];
            float4 e1 = *(const float4*)&embT[dd][vv8 + 4];
            float4 dg = *(const float4*)&diagT[dd][cc4];
            float ev[8] = {e0.x, e0.y, e0.z, e0.w, e1.x, e1.y, e1.z, e1.w};
            float dv[4] = {dg.x, dg.y, dg.z, dg.w};
            #pragma unroll
            for (int i = 0; i < 8; i++)
                #pragma unroll
                for (int j = 0; j < 4; j++)
                    acc[i][j] = fmaf(ev[i], dv[j], acc[i][j]);
        }
        __syncthreads();
    }

    const int c = c0 + cc4;
    if (c + 3 >= C_ && c >= C_) return;
    if (c >= C_) return;
    float bs[4], ws[4];
    #pragma unroll
    for (int j = 0; j < 4; j++) { bs[j] = bias[c + j]; ws[j] = wc[c + j]; }
    #pragma unroll
    for (int i = 0; i < 8; i++) {
        int v = v0 + vv8 + i;
        if (v >= V_) break;
        float4 o;
        o.x = fmaxf(acc[i][0] + bs[0], ws[0]);
        o.y = fmaxf(acc[i][1] + bs[1], ws[1]);
        o.z = fmaxf(acc[i][2] + bs[2], ws[2]);
        o.w = fmaxf(acc[i][3] + bs[3], ws[3]);
        *(float4*)&mt[(size_t)v * C_ + c] = o;
    }
}

// ---------------------------------------------------------------------------
// K2: scores[b][p] = max over t in [e-1, len-1] of
//        sum_{i=0}^{e-1} mt[doc[b][t-e+1+i]][p*6+i]
// One block per (b,p); 256 threads parallel over window positions t.
// ---------------------------------------------------------------------------
__global__ __launch_bounds__(256) void k_scan(const float* __restrict__ mt,
                                              const int* __restrict__ docs,
                                              const int* __restrict__ doc_lens,
                                              float* __restrict__ scores) {
    const int blk = blockIdx.x;
    const int b = blk / P_;
    const int p = blk - b * P_;
    const int e = 3 + p / 25;          // END_IDX[p] = pattern_len - 1
    const int len = doc_lens[b];
    const int tid = threadIdx.x;

    __shared__ int sdoc[T_];
    for (int q = tid; q < T_; q += 256) sdoc[q] = docs[b * T_ + q];
    __syncthreads();

    const float* mtp = mt + p * 6;
    float mx = -INFINITY;
    for (int t = e - 1 + tid; t < len; t += 256) {
        float s = 0.f;
        const int base = t - e + 1;
        for (int i = 0; i < e; i++)
            s += mtp[(size_t)sdoc[base + i] * C_ + i];
        mx = fmaxf(mx, s);
    }

    // block max-reduce (wave64 shuffle + cross-wave LDS)
    #pragma unroll
    for (int off = 32; off > 0; off >>= 1)
        mx = fmaxf(mx, __shfl_down(mx, off, 64));
    __shared__ float wmax[4];
    if ((tid & 63) == 0) wmax[tid >> 6] = mx;
    __syncthreads();
    if (tid == 0) {
        float m = fmaxf(fmaxf(wmax[0], wmax[1]), fmaxf(wmax[2], wmax[3]));
        scores[b * P_ + p] = m;
    }
}

// ---------------------------------------------------------------------------
// K3: masked layernorm over P, binarize (>0), then out = bin @ lw.T + lb
// One block per batch row.
// ---------------------------------------------------------------------------
__global__ __launch_bounds__(128) void k_final(const float* __restrict__ scores,
                                               const float* __restrict__ lw,
                                               const float* __restrict__ lb,
                                               float* __restrict__ out) {
    const int b = blockIdx.x;
    const int tid = threadIdx.x;
    __shared__ float sh[P_];
    __shared__ float stats[2];

    float s = 0.f;
    bool fin = false;
    if (tid < P_) {
        s = scores[b * P_ + tid];
        fin = !isinf(s);
        sh[tid] = s;
    }
    __syncthreads();
    if (tid == 0) {
        int n = 0; float sum = 0.f;
        for (int p = 0; p < P_; p++) {
            float x = sh[p];
            if (!isinf(x)) { n++; sum += x; }
        }
        float mean = sum / (float)n;
        float var = 0.f;
        for (int p = 0; p < P_; p++) {
            float x = sh[p];
            if (!isinf(x)) { float d = x - mean; var += d * d; }
        }
        var /= (float)n;
        stats[0] = mean;
        stats[1] = 1.f / sqrtf(var + 1e-5f);
    }
    __syncthreads();
    if (tid < P_) {
        float norm = fin ? (s - stats[0]) * stats[1] : s;
        sh[tid] = (norm > 0.f) ? 1.f : 0.f;
    }
    __syncthreads();
    if (tid < NC_) {
        float accv = lb[tid];
        for (int p = 0; p < P_; p++) accv += sh[p] * lw[tid * P_ + p];
        out[b * NC_ + tid] = accv;
    }
}

extern "C" void kernel_launch(void* const* d_in, const int* in_sizes, int n_in,
                              void* d_out, int out_size, void* d_ws, size_t ws_size,
                              hipStream_t stream) {
    const float* emb   = (const float*)d_in[0];   // (300, 10000)
    const float* diags = (const float*)d_in[1];   // (600, 300)
    const float* bias  = (const float*)d_in[2];   // (600, 1)
    const float* wc    = (const float*)d_in[3];   // (100, 6) flat = 600
    const float* lw    = (const float*)d_in[4];   // (2, 100)
    const float* lb    = (const float*)d_in[5];   // (2,)
    const int*   docs  = (const int*)d_in[6];     // (32, 2048)
    const int*   dlens = (const int*)d_in[7];     // (32,)
    float* out = (float*)d_out;                   // (32, 2)

    float* mt     = (float*)d_ws;                               // 10000*600*4 = 24 MB
    float* scores = (float*)((char*)d_ws + (size_t)V_ * C_ * 4); // 32*100*4

    k_gemm<<<dim3(79, 10), 256, 0, stream>>>(emb, diags, bias, wc, mt);
    k_scan<<<dim3(B_ * P_), 256, 0, stream>>>(mt, docs, dlens, scores);
    k_final<<<dim3(B_), 128, 0, stream>>>(scores, lw, lb, out);
}

// Round 2
// 222.084 us; speedup vs baseline: 1.3439x; 1.3439x over previous
//
#include <hip/hip_runtime.h>
#include <hip/hip_bf16.h>
#include <cmath>

#define V_   10000
#define D_   300
#define P_   100
#define B_   32
#define T_   2048
#define C_   600   // P * (MAXL-1)
#define NC_  2

// ---------------------------------------------------------------------------
// K1: mt[v][c] = max( (diags @ emb)[c][v] + bias[c], wc_flat[c] )
// Tile 128v x 64c, 256 threads, micro 8v x 4c (two v-quads of 4).
// Conflict-free LDS reads: embT float4 at (tid&15)*4 spans 256B (2-way = free),
// diagT float4 at (tid>>4)*4 is a 4-address broadcast.
// Register-prefetch double buffering over 10 K-chunks of 30.
// ---------------------------------------------------------------------------
__global__ __launch_bounds__(256) void k_gemm(const float* __restrict__ emb,
                                              const float* __restrict__ diags,
                                              const float* __restrict__ bias,
                                              const float* __restrict__ wc,
                                              float* __restrict__ mt) {
    __shared__ __align__(16) float embT[30][128];
    __shared__ __align__(16) float diagT[30][64];
    const int v0  = blockIdx.x * 128;
    const int c0  = blockIdx.y * 64;
    const int tid = threadIdx.x;

    const int vq = (tid & 15) * 4;   // v quad base within each 64-wide half
    const int cq = (tid >> 4) * 4;   // c quad base

    const int vv    = tid & 127;     // emb staging column
    const int dhalf = tid >> 7;      // emb staging row parity
    const bool vok  = (v0 + vv) < V_;

    float acc[8][4];
    #pragma unroll
    for (int i = 0; i < 8; i++)
        #pragma unroll
        for (int j = 0; j < 4; j++) acc[i][j] = 0.f;

    float rA[15];
    float rB[8];

    auto load_chunk = [&](int d0) {
        #pragma unroll
        for (int r = 0; r < 15; r++) {
            int dd = r * 2 + dhalf;
            rA[r] = vok ? emb[(d0 + dd) * V_ + v0 + vv] : 0.f;
        }
        #pragma unroll
        for (int k = 0; k < 8; k++) {
            int q = tid + k * 256;           // q < 1920 = 64*30
            if (q < 1920) {
                int cc = q / 30, dd = q - cc * 30;
                int c  = c0 + cc;
                rB[k] = (c < C_) ? diags[c * D_ + d0 + dd] : 0.f;
            } else rB[k] = 0.f;
        }
    };

    load_chunk(0);

    for (int ch = 0; ch < 10; ++ch) {
        if (ch) __syncthreads();
        // regs -> LDS
        #pragma unroll
        for (int r = 0; r < 15; r++) embT[r * 2 + dhalf][vv] = rA[r];
        #pragma unroll
        for (int k = 0; k < 8; k++) {
            int q = tid + k * 256;
            if (q < 1920) {
                int cc = q / 30, dd = q - cc * 30;
                diagT[dd][cc] = rB[k];
            }
        }
        __syncthreads();
        if (ch < 9) load_chunk((ch + 1) * 30);  // overlaps with compute below

        #pragma unroll
        for (int dd = 0; dd < 30; dd++) {
            float4 e0 = *(const float4*)&embT[dd][vq];
            float4 e1 = *(const float4*)&embT[dd][64 + vq];
            float4 dg = *(const float4*)&diagT[dd][cq];
            float ev[8] = {e0.x, e0.y, e0.z, e0.w, e1.x, e1.y, e1.z, e1.w};
            float dv[4] = {dg.x, dg.y, dg.z, dg.w};
            #pragma unroll
            for (int i = 0; i < 8; i++)
                #pragma unroll
                for (int j = 0; j < 4; j++)
                    acc[i][j] = fmaf(ev[i], dv[j], acc[i][j]);
        }
    }

    const int c = c0 + cq;
    if (c >= C_) return;
    float bs[4], ws[4];
    #pragma unroll
    for (int j = 0; j < 4; j++) { bs[j] = bias[c + j]; ws[j] = wc[c + j]; }
    #pragma unroll
    for (int h = 0; h < 2; h++) {
        #pragma unroll
        for (int i = 0; i < 4; i++) {
            int v = v0 + h * 64 + vq + i;
            if (v < V_) {
                float4 o;
                o.x = fmaxf(acc[h * 4 + i][0] + bs[0], ws[0]);
                o.y = fmaxf(acc[h * 4 + i][1] + bs[1], ws[1]);
                o.z = fmaxf(acc[h * 4 + i][2] + bs[2], ws[2]);
                o.w = fmaxf(acc[h * 4 + i][3] + bs[3], ws[3]);
                *(float4*)&mt[(size_t)v * C_ + c] = o;
            }
        }
    }
}

// ---------------------------------------------------------------------------
// K2: scores[b][p] = max over window-starts t of sum_{i<e} mt[doc[t+i]][p*6+i]
// One block per (b,p), p-major with XCD swizzle so each XCD's L2 holds a
// ~3 MB slice of mt. Per token: ONE contiguous 16-24B gather into LDS
// (transposed m7i[7][*] -> stride-1, conflict-free), then windows from LDS.
// ---------------------------------------------------------------------------
#define CH_ 1024
__global__ __launch_bounds__(256) void k_scan(const float* __restrict__ mt,
                                              const int* __restrict__ docs,
                                              const int* __restrict__ doc_lens,
                                              float* __restrict__ scores) {
    const int bid  = blockIdx.x;
    const int orig = (bid & 7) * 400 + (bid >> 3);   // bijective: 3200 = 8*400
    const int p = orig >> 5;
    const int b = orig & 31;
    const int e   = 3 + p / 25;        // window length in {3,4,5,6}
    const int len = doc_lens[b];
    const int tid = threadIdx.x;

    const float* mtp = mt + p * 6;

    __shared__ float m7i[6][CH_ + 12];
    __shared__ float wmax[4];

    float mx = -INFINITY;

    for (int s = 0; s < T_; s += CH_) {
        const int count = min(CH_ + e - 1, T_ - s);   // tokens s .. s+count-1
        if (s) __syncthreads();
        for (int q = tid; q < count; q += 256) {
            const int row = docs[b * T_ + s + q];
            const float* src = mtp + (size_t)row * C_;  // 8B aligned always
            float2 v0 = *(const float2*)(src);
            float2 v1 = *(const float2*)(src + 2);
            m7i[0][q] = v0.x; m7i[1][q] = v0.y;
            m7i[2][q] = v1.x; m7i[3][q] = v1.y;
            if (e > 4) {                      // block-uniform branch
                float2 v2 = *(const float2*)(src + 4);
                m7i[4][q] = v2.x; m7i[5][q] = v2.y;
            }
        }
        __syncthreads();

        const int tmax = min(s + CH_, len - e + 1);   // window starts t < tmax
        for (int t = s + tid; t < tmax; t += 256) {
            const int q = t - s;
            float sum = m7i[0][q];
            for (int i = 1; i < e; i++) sum += m7i[i][q + i];
            mx = fmaxf(mx, sum);
        }
    }

    #pragma unroll
    for (int off = 32; off > 0; off >>= 1)
        mx = fmaxf(mx, __shfl_down(mx, off, 64));
    if ((tid & 63) == 0) wmax[tid >> 6] = mx;
    __syncthreads();
    if (tid == 0) {
        float m = fmaxf(fmaxf(wmax[0], wmax[1]), fmaxf(wmax[2], wmax[3]));
        scores[b * P_ + p] = m;
    }
}

// ---------------------------------------------------------------------------
// K3: masked layernorm over P, binarize (>0), then out = bin @ lw.T + lb
// ---------------------------------------------------------------------------
__global__ __launch_bounds__(128) void k_final(const float* __restrict__ scores,
                                               const float* __restrict__ lw,
                                               const float* __restrict__ lb,
                                               float* __restrict__ out) {
    const int b = blockIdx.x;
    const int tid = threadIdx.x;
    __shared__ float sh[P_];
    __shared__ float stats[2];

    float s = 0.f;
    bool fin = false;
    if (tid < P_) {
        s = scores[b * P_ + tid];
        fin = !isinf(s);
        sh[tid] = s;
    }
    __syncthreads();
    if (tid == 0) {
        int n = 0; float sum = 0.f;
        for (int p = 0; p < P_; p++) {
            float x = sh[p];
            if (!isinf(x)) { n++; sum += x; }
        }
        float mean = sum / (float)n;
        float var = 0.f;
        for (int p = 0; p < P_; p++) {
            float x = sh[p];
            if (!isinf(x)) { float d = x - mean; var += d * d; }
        }
        var /= (float)n;
        stats[0] = mean;
        stats[1] = 1.f / sqrtf(var + 1e-5f);
    }
    __syncthreads();
    if (tid < P_) {
        float norm = fin ? (s - stats[0]) * stats[1] : s;
        sh[tid] = (norm > 0.f) ? 1.f : 0.f;
    }
    __syncthreads();
    if (tid < NC_) {
        float accv = lb[tid];
        for (int p = 0; p < P_; p++) accv += sh[p] * lw[tid * P_ + p];
        out[b * NC_ + tid] = accv;
    }
}

extern "C" void kernel_launch(void* const* d_in, const int* in_sizes, int n_in,
                              void* d_out, int out_size, void* d_ws, size_t ws_size,
                              hipStream_t stream) {
    const float* emb   = (const float*)d_in[0];   // (300, 10000)
    const float* diags = (const float*)d_in[1];   // (600, 300)
    const float* bias  = (const float*)d_in[2];   // (600, 1)
    const float* wc    = (const float*)d_in[3];   // (100, 6)
    const float* lw    = (const float*)d_in[4];   // (2, 100)
    const float* lb    = (const float*)d_in[5];   // (2,)
    const int*   docs  = (const int*)d_in[6];     // (32, 2048)
    const int*   dlens = (const int*)d_in[7];     // (32,)
    float* out = (float*)d_out;                   // (32, 2)

    float* mt     = (float*)d_ws;                                // 24 MB
    float* scores = (float*)((char*)d_ws + (size_t)V_ * C_ * 4);

    k_gemm<<<dim3(79, 10), 256, 0, stream>>>(emb, diags, bias, wc, mt);
    k_scan<<<dim3(B_ * P_), 256, 0, stream>>>(mt, docs, dlens, scores);
    k_final<<<dim3(B_), 128, 0, stream>>>(scores, lw, lb, out);
}

// Round 4
// 187.815 us; speedup vs baseline: 1.5892x; 1.1825x over previous
//
#include <hip/hip_runtime.h>
#include <hip/hip_bf16.h>
#include <cmath>
#include <cstdint>

#define V_   10000
#define D_   300
#define P_   100
#define B_   32
#define T_   2048
#define NC_  2
#define CP_  450      // packed (used) columns: sum over p of e(p), e = 3+p/25
#define STMT 452      // packed row stride in floats (16B aligned)

// p-group boundaries (8 groups, <=60 cols each) and packed-col starts
__device__ __constant__ int GP0c[9] = {0, 19, 33, 46, 58, 69, 80, 90, 100};
__device__ __constant__ int GC0c[9] = {0, 57, 107, 159, 215, 270, 330, 390, 450};

// packed col -> original diag/bias/wc row (p*6 + i)
__device__ __forceinline__ int maprow(int c) {
    if (c < 75)  return (c / 3) * 6 + c % 3;
    if (c < 175) { int q = c - 75;  return (25 + q / 4) * 6 + q % 4; }
    if (c < 300) { int q = c - 175; return (50 + q / 5) * 6 + q % 5; }
    int q = c - 300; return (75 + q / 6) * 6 + q % 6;
}

__device__ __forceinline__ void load_lds16(const float* g, float* l) {
    __builtin_amdgcn_global_load_lds((const __attribute__((address_space(1))) void*)g,
                                     (__attribute__((address_space(3))) void*)l, 16, 0, 0);
}
__device__ __forceinline__ void load_lds4(const float* g, float* l) {
    __builtin_amdgcn_global_load_lds((const __attribute__((address_space(1))) void*)g,
                                     (__attribute__((address_space(3))) void*)l, 4, 0, 0);
}

// ---------------------------------------------------------------------------
// K1: mt[v][cpacked] = max(dot(diags[maprow(c)], emb[:,v]) + bias, wc)
// 128v x 64c tile, 256 threads, micro 8v x 4c. Staging via global_load_lds
// (no VGPR round-trip, no ds_write conflicts), LDS double-buffered.
// ---------------------------------------------------------------------------
__global__ __launch_bounds__(256) void k_gemm(const float* __restrict__ emb,
                                              const float* __restrict__ diags,
                                              const float* __restrict__ bias,
                                              const float* __restrict__ wc,
                                              float* __restrict__ mt) {
    __shared__ __align__(16) float embT[2][30][128];
    __shared__ __align__(16) float diagT[2][30][68];   // 68: b128 reads conflict-free
    const int v0  = blockIdx.x * 128;
    const int c0  = blockIdx.y * 64;
    const int tid = threadIdx.x;
    const int lane = tid & 63;
    const int wid  = tid >> 6;

    const int vq = (tid & 15) * 4;
    const int cq = (tid >> 4) * 4;

    // per-lane global sources for staging
    const int vcl  = min(v0 + (lane & 31) * 4, V_ - 4);  // clamp tail (masked at store)
    const int erow = lane >> 5;                          // 0/1: which of 2 rows per instr
    const int drow = maprow(min(c0 + lane, CP_ - 1));    // diag row for this lane's col

    float acc[8][4];
    #pragma unroll
    for (int i = 0; i < 8; i++)
        #pragma unroll
        for (int j = 0; j < 4; j++) acc[i][j] = 0.f;

    auto stage = [&](int buf, int d0) {
        #pragma unroll
        for (int k = 0; k < 15; k++)            // 15 instrs x 1KB = embT chunk
            if ((k & 3) == wid)
                load_lds16(emb + (size_t)(d0 + 2 * k + erow) * V_ + vcl,
                           &embT[buf][2 * k][0]);
        #pragma unroll
        for (int dd = 0; dd < 30; dd++)         // 30 instrs x 256B = diagT chunk
            if ((dd & 3) == wid)
                load_lds4(diags + (size_t)drow * D_ + d0 + dd,
                          &diagT[buf][dd][0]);
    };

    stage(0, 0);
    __syncthreads();

    for (int ch = 0; ch < 10; ch++) {
        if (ch < 9) stage((ch + 1) & 1, (ch + 1) * 30);  // async prefetch
        const int buf = ch & 1;
        #pragma unroll
        for (int dd = 0; dd < 30; dd++) {
            float4 e0 = *(const float4*)&embT[buf][dd][vq];
            float4 e1 = *(const float4*)&embT[buf][dd][64 + vq];
            float4 dg = *(const float4*)&diagT[buf][dd][cq];
            float ev[8] = {e0.x, e0.y, e0.z, e0.w, e1.x, e1.y, e1.z, e1.w};
            float dv[4] = {dg.x, dg.y, dg.z, dg.w};
            #pragma unroll
            for (int i = 0; i < 8; i++)
                #pragma unroll
                for (int j = 0; j < 4; j++)
                    acc[i][j] = fmaf(ev[i], dv[j], acc[i][j]);
        }
        __syncthreads();   // drains prefetch vmcnt + protects buf reuse
    }

    const int c = c0 + cq;
    if (c >= CP_) return;          // (c==448 writes cols 450/451 = row pad, harmless)
    float bs[4], ws[4];
    #pragma unroll
    for (int j = 0; j < 4; j++) {
        int rr = maprow(min(c + j, CP_ - 1));
        bs[j] = bias[rr]; ws[j] = wc[rr];
    }
    #pragma unroll
    for (int h = 0; h < 2; h++)
        #pragma unroll
        for (int i = 0; i < 4; i++) {
            int v = v0 + h * 64 + vq + i;
            if (v < V_) {
                float4 o;
                o.x = fmaxf(acc[h * 4 + i][0] + bs[0], ws[0]);
                o.y = fmaxf(acc[h * 4 + i][1] + bs[1], ws[1]);
                o.z = fmaxf(acc[h * 4 + i][2] + bs[2], ws[2]);
                o.w = fmaxf(acc[h * 4 + i][3] + bs[3], ws[3]);
                *(float4*)&mt[(size_t)v * STMT + c] = o;
            }
        }
}

// ---------------------------------------------------------------------------
// K2: block = (b, t-segment of 128 starts, p-group). Stage 133 token rows x
// <=60 packed cols into LDS via coalesced global_load_lds; thread t computes
// all its group's window sums from LDS (odd stride 61 -> conflict-free).
// part[ts][b][p] = max over this segment's starts.
// ---------------------------------------------------------------------------
#define NT_ 128
#define NR_ (NT_ + 5)
#define ST_ 61

__global__ __launch_bounds__(256) void k_scan(const float* __restrict__ mt,
                                              const int* __restrict__ docs,
                                              const int* __restrict__ doc_lens,
                                              float* __restrict__ part) {
    __shared__ float sm[NR_][ST_];
    __shared__ int   rowbuf[NR_];
    __shared__ float wred[4][20];

    const int bid = blockIdx.x;
    const int pg  = bid & 7;            // == XCD on round-robin dispatch
    const int bts = bid >> 3;
    const int ts  = bts & 15;
    const int b   = bts >> 4;
    const int ts0 = ts * NT_;
    const int tid = threadIdx.x;
    const int lane = tid & 63;
    const int wid  = tid >> 6;

    const int c0 = GC0c[pg];
    const int cg = GC0c[pg + 1] - c0;
    const int p0 = GP0c[pg], p1 = GP0c[pg + 1];
    const int np = p1 - p0;
    const int nrows = min(NR_, T_ - ts0);
    const int len = doc_lens[b];

    for (int q = tid; q < nrows; q += 256) rowbuf[q] = docs[b * T_ + ts0 + q];
    __syncthreads();

    // gather: wave w stages rows w, w+4, ... ; row indices broadcast via shfl
    int rv = 0;
    { int myr = wid + 4 * lane; if (myr < nrows) rv = rowbuf[myr]; }
    const int kmax = (nrows - wid + 3) >> 2;
    for (int k = 0; k < kmax; k++) {
        const int rowv = __shfl(rv, k, 64);
        const int r = wid + 4 * k;
        if (lane < cg)
            load_lds4(mt + (size_t)rowv * STMT + c0 + lane, &sm[r][0]);
    }
    __syncthreads();

    // compute: thread t = tid&127; halves of p-list on waves {0,1} / {2,3}
    const int t = tid & 127;
    const int h = tid >> 7;
    const int halfsz = (np + 1) >> 1;
    const int pa = h ? (p0 + halfsz) : p0;
    const int pb = h ? p1 : (p0 + halfsz);

    int lb = 0;
    for (int p = p0; p < pa; p++) lb += 3 + p / 25;

    for (int p = pa; p < pb; p++) {
        const int e = 3 + p / 25;
        float s = sm[t][lb];
        for (int i = 1; i < e; i++) s += sm[t + i][lb + i];
        float val = (ts0 + t + e <= len) ? s : -INFINITY;
        #pragma unroll
        for (int off = 32; off > 0; off >>= 1)
            val = fmaxf(val, __shfl_down(val, off, 64));
        if (lane == 0) wred[wid][p - p0] = val;
        lb += e;
    }
    __syncthreads();

    if (tid < np) {
        const bool h2 = tid >= halfsz;
        float m = h2 ? fmaxf(wred[2][tid], wred[3][tid])
                     : fmaxf(wred[0][tid], wred[1][tid]);
        part[((size_t)ts * B_ + b) * P_ + p0 + tid] = m;
    }
}

// ---------------------------------------------------------------------------
// K3: reduce 16 segments, masked layernorm over P, binarize, linear.
// ---------------------------------------------------------------------------
__global__ __launch_bounds__(128) void k_final(const float* __restrict__ part,
                                               const float* __restrict__ lw,
                                               const float* __restrict__ lb,
                                               float* __restrict__ out) {
    const int b = blockIdx.x;
    const int tid = threadIdx.x;
    __shared__ float sh[P_];
    __shared__ float stats[2];

    float s = -INFINITY;
    bool fin = false;
    if (tid < P_) {
        for (int sg = 0; sg < 16; sg++)
            s = fmaxf(s, part[((size_t)sg * B_ + b) * P_ + tid]);
        fin = !isinf(s);
        sh[tid] = s;
    }
    __syncthreads();
    if (tid == 0) {
        int n = 0; float sum = 0.f;
        for (int p = 0; p < P_; p++) {
            float x = sh[p];
            if (!isinf(x)) { n++; sum += x; }
        }
        float mean = sum / (float)n;
        float var = 0.f;
        for (int p = 0; p < P_; p++) {
            float x = sh[p];
            if (!isinf(x)) { float d = x - mean; var += d * d; }
        }
        var /= (float)n;
        stats[0] = mean;
        stats[1] = 1.f / sqrtf(var + 1e-5f);
    }
    __syncthreads();
    if (tid < P_) {
        float norm = fin ? (s - stats[0]) * stats[1] : s;
        sh[tid] = (norm > 0.f) ? 1.f : 0.f;
    }
    __syncthreads();
    if (tid < NC_) {
        float accv = lb[tid];
        for (int p = 0; p < P_; p++) accv += sh[p] * lw[tid * P_ + p];
        out[b * NC_ + tid] = accv;
    }
}

extern "C" void kernel_launch(void* const* d_in, const int* in_sizes, int n_in,
                              void* d_out, int out_size, void* d_ws, size_t ws_size,
                              hipStream_t stream) {
    const float* emb   = (const float*)d_in[0];   // (300, 10000)
    const float* diags = (const float*)d_in[1];   // (600, 300)
    const float* bias  = (const float*)d_in[2];   // (600, 1)
    const float* wc    = (const float*)d_in[3];   // (100, 6)
    const float* lw    = (const float*)d_in[4];   // (2, 100)
    const float* lb    = (const float*)d_in[5];   // (2,)
    const int*   docs  = (const int*)d_in[6];     // (32, 2048)
    const int*   dlens = (const int*)d_in[7];     // (32,)
    float* out = (float*)d_out;                   // (32, 2)

    float* mt   = (float*)d_ws;                                    // 10000*452*4 = 18.08 MB
    float* part = (float*)((char*)d_ws + (size_t)V_ * STMT * 4);   // 16*32*100*4

    k_gemm<<<dim3(79, 8), 256, 0, stream>>>(emb, diags, bias, wc, mt);
    k_scan<<<dim3(B_ * 16 * 8), 256, 0, stream>>>(mt, docs, dlens, part);
    k_final<<<dim3(B_), 128, 0, stream>>>(part, lw, lb, out);
}

// Round 5
// 180.490 us; speedup vs baseline: 1.6536x; 1.0406x over previous
//
#include <hip/hip_runtime.h>
#include <hip/hip_bf16.h>
#include <cmath>
#include <cstdint>

#define V_   10000
#define D_   300
#define P_   100
#define B_   32
#define T_   2048
#define NC_  2
#define CP_  450      // packed used cols: sum_p e(p), e = 3+p/25
#define CPAD 464      // padded packed-col stride (16 floats x 29 c-tiles)

__device__ __constant__ int PS_[9] = {0, 13, 26, 38, 51, 63, 76, 88, 100};

// packed col -> original diag/bias/wc row (p*6 + i)
__device__ __forceinline__ int maprow(int c) {
    if (c < 75)  return (c / 3) * 6 + c % 3;
    if (c < 175) { int q = c - 75;  return (25 + q / 4) * 6 + q % 4; }
    if (c < 300) { int q = c - 175; return (50 + q / 5) * 6 + q % 5; }
    int q = c - 300; return (75 + q / 6) * 6 + q % 6;
}
// first packed col of pattern p
__device__ __forceinline__ int cstart(int p) {
    if (p < 25) return 3 * p;
    if (p < 50) return 75 + 4 * (p - 25);
    if (p < 75) return 175 + 5 * (p - 50);
    return 300 + 6 * (p - 75);
}
// monotone float<->uint for exact deterministic atomicMax
__device__ __forceinline__ uint32_t fkey(float v) {
    uint32_t u = __float_as_uint(v);
    return (u & 0x80000000u) ? ~u : (u | 0x80000000u);
}
__device__ __forceinline__ float fdec(uint32_t k) {
    uint32_t u = (k & 0x80000000u) ? (k ^ 0x80000000u) : ~k;
    return __uint_as_float(u);
}

__device__ __forceinline__ void load_lds16(const float* g, float* l) {
    __builtin_amdgcn_global_load_lds((const __attribute__((address_space(1))) void*)g,
                                     (__attribute__((address_space(3))) void*)l, 16, 0, 0);
}

// ---------------------------------------------------------------------------
// K0: build dT[d][cp] = diags[maprow(cp)][d] (zero-padded), bp/wp packed,
// and init scoresU to key(-inf).
// ---------------------------------------------------------------------------
__global__ __launch_bounds__(256) void k_tr(const float* __restrict__ diags,
                                            const float* __restrict__ bias,
                                            const float* __restrict__ wc,
                                            float* __restrict__ dT,
                                            float* __restrict__ bp,
                                            float* __restrict__ wp,
                                            uint32_t* __restrict__ scoresU) {
    const int idx = blockIdx.x * 256 + threadIdx.x;
    if (idx < B_ * P_) scoresU[idx] = 0x007FFFFFu;     // fkey(-inf)
    if (idx < CPAD) {
        float b = 0.f, w = 0.f;
        if (idx < CP_) { int r = maprow(idx); b = bias[r]; w = wc[r]; }
        bp[idx] = b; wp[idx] = w;
    }
    if (idx < D_ * CPAD) {
        const int d = idx / CPAD, cp = idx - d * CPAD;
        dT[idx] = (cp < CP_) ? diags[maprow(cp) * D_ + d] : 0.f;
    }
}

// ---------------------------------------------------------------------------
// K1: mt[v][cp] = max(dot + bias, wc). Block: 4 waves = 2v x 2c, tile
// 512v x 16c. Lane holds 4v (ONE ds_read_b128/dd); the 8 diag values are
// wave-uniform (scalar loads from dT) -> LDS pipe carries only emb.
// Bijective XCD-chunked block map keeps each XCD's emb slice L2-resident.
// ---------------------------------------------------------------------------
__global__ __launch_bounds__(256) void k_gemm(const float* __restrict__ emb,
                                              const float* __restrict__ dT,
                                              const float* __restrict__ bp,
                                              const float* __restrict__ wp,
                                              float* __restrict__ mt) {
    __shared__ __align__(16) float embT[2][10][512];
    const int bid = blockIdx.x;                 // 580 blocks = 20 v x 29 c
    const int xcd = bid & 7, ii = bid >> 3;
    const int ord = (xcd < 4) ? (xcd * 73 + ii) : (292 + (xcd - 4) * 72 + ii);
    const int vt = ord / 29, ct = ord - vt * 29;
    const int v0 = vt * 512, c0 = ct * 16;

    const int tid  = threadIdx.x;
    const int lane = tid & 63;
    const int wid  = tid >> 6;
    const int widv = wid & 1;
    const int cb   = __builtin_amdgcn_readfirstlane(c0 + (wid >> 1) * 8);

    float acc[4][8] = {};

    auto stage = [&](int buf, int d0) {
        for (int r = wid; r < 10; r += 4) {
            #pragma unroll
            for (int h = 0; h < 2; ++h) {
                int vsrc = v0 + h * 256 + (lane << 2);
                vsrc = min(vsrc, V_ - 4);                 // tail clamp (masked at store)
                load_lds16(emb + (size_t)(d0 + r) * V_ + vsrc, &embT[buf][r][h * 256]);
            }
        }
    };

    stage(0, 0);
    __syncthreads();

    for (int ch = 0; ch < 30; ++ch) {
        if (ch < 29) stage((ch + 1) & 1, (ch + 1) * 10);  // async prefetch -> other buf
        const int buf = ch & 1;
        #pragma unroll
        for (int dd = 0; dd < 10; ++dd) {
            const float4 ev = *(const float4*)&embT[buf][dd][widv * 256 + (lane << 2)];
            const float* dr = dT + (size_t)(ch * 10 + dd) * CPAD + cb;   // uniform
            float dg[8];
            #pragma unroll
            for (int j = 0; j < 8; ++j) dg[j] = dr[j];
            const float evf[4] = {ev.x, ev.y, ev.z, ev.w};
            #pragma unroll
            for (int i4 = 0; i4 < 4; ++i4)
                #pragma unroll
                for (int j = 0; j < 8; ++j)
                    acc[i4][j] = fmaf(evf[i4], dg[j], acc[i4][j]);
        }
        __syncthreads();   // drains prefetch vmcnt + protects buf reuse
    }

    float bs[8], ws2[8];
    #pragma unroll
    for (int j = 0; j < 8; ++j) { bs[j] = bp[cb + j]; ws2[j] = wp[cb + j]; }
    const int vb = v0 + widv * 256 + (lane << 2);
    #pragma unroll
    for (int i4 = 0; i4 < 4; ++i4) {
        const int v = vb + i4;
        if (v < V_) {
            float4 o0, o1;
            o0.x = fmaxf(acc[i4][0] + bs[0], ws2[0]);
            o0.y = fmaxf(acc[i4][1] + bs[1], ws2[1]);
            o0.z = fmaxf(acc[i4][2] + bs[2], ws2[2]);
            o0.w = fmaxf(acc[i4][3] + bs[3], ws2[3]);
            o1.x = fmaxf(acc[i4][4] + bs[4], ws2[4]);
            o1.y = fmaxf(acc[i4][5] + bs[5], ws2[5]);
            o1.z = fmaxf(acc[i4][6] + bs[6], ws2[6]);
            o1.w = fmaxf(acc[i4][7] + bs[7], ws2[7]);
            *(float4*)&mt[(size_t)v * CPAD + cb]     = o0;
            *(float4*)&mt[(size_t)v * CPAD + cb + 4] = o1;
        }
    }
}

// ---------------------------------------------------------------------------
// K2: block = (b, 32 window-starts). Stage 37 full token rows (450 cols,
// contiguous 1.8KB bursts, L3-resident table) into LDS; thread (t, pset)
// computes window sums for its ~13 patterns; width-32 shuffle max-reduce;
// exact deterministic atomicMax(uint-key) into scoresU.
// ---------------------------------------------------------------------------
__global__ __launch_bounds__(256) void k_scan(const float* __restrict__ mt,
                                              const int* __restrict__ docs,
                                              const int* __restrict__ doc_lens,
                                              uint32_t* __restrict__ scoresU) {
    __shared__ float sm[37][453];      // odd stride -> conflict-free diagonals
    __shared__ int rowbuf[37];
    const int bid = blockIdx.x;        // 2048 = 64 ts x 32 b
    const int b = bid & 31, ts = bid >> 5;
    const int ts0 = ts * 32;
    const int tid = threadIdx.x;
    const int lane = tid & 63, wid = tid >> 6;
    const int len = doc_lens[b];
    const int nst = min(37, T_ - ts0);

    for (int q = tid; q < nst; q += 256) rowbuf[q] = docs[b * T_ + ts0 + q];
    __syncthreads();
    for (int r = wid; r < nst; r += 4) {
        const float* src = mt + (size_t)rowbuf[r] * CPAD;
        load_lds16(src + (lane << 2), &sm[r][0]);
        if (lane < 49) load_lds16(src + 256 + (lane << 2), &sm[r][256]);
    }
    __syncthreads();

    const int t = tid & 31;
    const int pset = tid >> 5;
    const int p0 = PS_[pset], p1 = PS_[pset + 1];
    for (int p = p0; p < p1; ++p) {
        const int e = 3 + p / 25;
        const int cb = cstart(p);
        float s = sm[t][cb];
        for (int i2 = 1; i2 < e; ++i2) s += sm[t + i2][cb + i2];
        float val = (ts0 + t + e <= len) ? s : -INFINITY;
        #pragma unroll
        for (int off = 16; off > 0; off >>= 1)
            val = fmaxf(val, __shfl_xor(val, off, 32));
        if (t == 0) atomicMax(&scoresU[b * P_ + p], fkey(val));
    }
}

// ---------------------------------------------------------------------------
// K3: decode keys, masked layernorm over P, binarize, linear.
// ---------------------------------------------------------------------------
__global__ __launch_bounds__(128) void k_final(const uint32_t* __restrict__ scoresU,
                                               const float* __restrict__ lw,
                                               const float* __restrict__ lb,
                                               float* __restrict__ out) {
    const int b = blockIdx.x;
    const int tid = threadIdx.x;
    __shared__ float sh[P_];
    __shared__ float stats[2];

    float s = 0.f;
    bool fin = false;
    if (tid < P_) {
        s = fdec(scoresU[b * P_ + tid]);
        fin = !isinf(s);
        sh[tid] = s;
    }
    __syncthreads();
    if (tid == 0) {
        int n = 0; float sum = 0.f;
        for (int p = 0; p < P_; p++) {
            float x = sh[p];
            if (!isinf(x)) { n++; sum += x; }
        }
        float mean = sum / (float)n;
        float var = 0.f;
        for (int p = 0; p < P_; p++) {
            float x = sh[p];
            if (!isinf(x)) { float d = x - mean; var += d * d; }
        }
        var /= (float)n;
        stats[0] = mean;
        stats[1] = 1.f / sqrtf(var + 1e-5f);
    }
    __syncthreads();
    if (tid < P_) {
        float norm = fin ? (s - stats[0]) * stats[1] : s;
        sh[tid] = (norm > 0.f) ? 1.f : 0.f;
    }
    __syncthreads();
    if (tid < NC_) {
        float accv = lb[tid];
        for (int p = 0; p < P_; p++) accv += sh[p] * lw[tid * P_ + p];
        out[b * NC_ + tid] = accv;
    }
}

extern "C" void kernel_launch(void* const* d_in, const int* in_sizes, int n_in,
                              void* d_out, int out_size, void* d_ws, size_t ws_size,
                              hipStream_t stream) {
    const float* emb   = (const float*)d_in[0];   // (300, 10000)
    const float* diags = (const float*)d_in[1];   // (600, 300)
    const float* bias  = (const float*)d_in[2];   // (600, 1)
    const float* wc    = (const float*)d_in[3];   // (100, 6)
    const float* lw    = (const float*)d_in[4];   // (2, 100)
    const float* lb    = (const float*)d_in[5];   // (2,)
    const int*   docs  = (const int*)d_in[6];     // (32, 2048)
    const int*   dlens = (const int*)d_in[7];     // (32,)
    float* out = (float*)d_out;                   // (32, 2)

    float*    mt      = (float*)d_ws;                               // 10000*464*4 = 18.56 MB
    float*    dT      = mt + (size_t)V_ * CPAD;                     // 300*464
    float*    bp      = dT + (size_t)D_ * CPAD;                     // 464
    float*    wp      = bp + CPAD;                                  // 464
    uint32_t* scoresU = (uint32_t*)(wp + CPAD);                     // 3200

    k_tr   <<<dim3(544),  256, 0, stream>>>(diags, bias, wc, dT, bp, wp, scoresU);
    k_gemm <<<dim3(580),  256, 0, stream>>>(emb, dT, bp, wp, mt);
    k_scan <<<dim3(2048), 256, 0, stream>>>(mt, docs, dlens, scoresU);
    k_final<<<dim3(B_),   128, 0, stream>>>(scoresU, lw, lb, out);
}